// Round 16
// baseline (36.851 us; speedup 1.0000x reference)
//
#include <hip/hip_runtime.h>

#define IN_F 8192
#define OUT_F 8192
#define BATCH 32
#define HALFG ((OUT_F / 2) * (IN_F / 128))  // 262144 groups in the hi-nibble half
#define NFRAG_HALF 16384                    // 256 k-steps * 64 lanes per batch-half

typedef _Float16 f16x2 __attribute__((ext_vector_type(2)));
typedef _Float16 f16x8 __attribute__((ext_vector_type(8)));
typedef float f32x4 __attribute__((ext_vector_type(4)));
typedef int i32x4 __attribute__((ext_vector_type(4)));

union AFrag { f16x8 v; i32x4 i4; };
union BFrag { f16x8 v; unsigned int u[4]; };
union F16x2U { f16x2 v; unsigned int u; };
union F16U { _Float16 v; unsigned short u; };

__device__ inline f16x2 dq_pair(unsigned int h_bits, f16x2 s2, f16x2 zs2) {
    F16x2U h; h.u = h_bits;
    const f16x2 c1024 = {(_Float16)1024.0f, (_Float16)1024.0f};
    f16x2 n = h.v - c1024;          // exact: n in [0,15]
    return n * s2 + zs2;            // v_pk_fma_f16
}

// x fp32 -> fp16, repacked into MFMA A-fragment order.
__global__ __launch_bounds__(256) void xcvt_kernel(const float* __restrict__ x,
                                                   f16x8* __restrict__ xc) {
    int t = blockIdx.x * 256 + threadIdx.x;  // 32768 frags
    int r = t & 15;
    int q = (t >> 4) & 3;
    int k32 = (t >> 6) & 255;
    int half = t >> 14;
    int b = half * 16 + r;
    int kb = k32 * 32 + q * 4;
    float4 x0 = *(const float4*)(x + (size_t)b * IN_F + kb);
    float4 x1 = *(const float4*)(x + (size_t)b * IN_F + kb + 16);
    f16x8 o;
    o[0] = (_Float16)x0.x; o[1] = (_Float16)x0.y; o[2] = (_Float16)x0.z; o[3] = (_Float16)x0.w;
    o[4] = (_Float16)x1.x; o[5] = (_Float16)x1.y; o[6] = (_Float16)x1.z; o[7] = (_Float16)x1.w;
    xc[t] = o;
}

__global__ __launch_bounds__(256) void bias_init_kernel(const float4* __restrict__ bias,
                                                        float4* __restrict__ out) {
    int i = blockIdx.x * 256 + threadIdx.x;
    out[i] = bias[i & 2047];
}

// 4 waves/block; wave owns 16 pair-rows (o, o+4096) x 32 batches. KSPLIT=16.
// LDS-staged xc slice; kg-clustered packed bursts; fp16 partials [ks][b][o]
// (R15 base). NEW: partial stores are NONTEMPORAL — single-use stream must
// not evict the L3-retained packed array (R8: FETCH 78MB<134MB retention).
template <int KSPLIT, bool FAST>
__global__ __launch_bounds__(256, 4) void qgemm_kernel(
    const float* __restrict__ xf, const f16x8* __restrict__ xc,
    const int* __restrict__ packed, const float* __restrict__ scale,
    const float* __restrict__ zero, void* __restrict__ outp) {
    constexpr int KCHUNK = IN_F / KSPLIT;      // 512
    constexpr int NKG = KCHUNK / 128;          // 4 groups
    constexpr int NIT = NKG * 4;               // 16 k-steps of 32
    const int tidx = threadIdx.x;
    const int w = tidx >> 6;
    const int lane = tidx & 63;
    const int r = lane & 15;
    const int q = lane >> 4;
    const int nb = blockIdx.x;                 // 0..63
    const int ks = blockIdx.y;                 // 0..KSPLIT-1
    const int pr = nb * 64 + w * 16 + r;       // packed row < 4096
    const int kbase = ks * KCHUNK;

    __shared__ __align__(16) f16x8 alds[2 * NIT * 64];   // 2048 frags = 32 KB

    if (FAST) {
        const size_t base0 = (size_t)ks * (NIT * 64);    // slice offset per half
#pragma unroll
        for (int j = 0; j < 8; ++j) {
            const int f = j * 256 + tidx;                // 0..2047
            const f16x8* src = (f < NIT * 64)
                                   ? (xc + base0 + f)
                                   : (xc + NFRAG_HALF + base0 + (f - NIT * 64));
            alds[f] = *src;
        }
        __syncthreads();
    }

    f32x4 acc[2][2] = {{{0.f, 0.f, 0.f, 0.f}, {0.f, 0.f, 0.f, 0.f}},
                       {{0.f, 0.f, 0.f, 0.f}, {0.f, 0.f, 0.f, 0.f}}};

    const int* pk = packed + (size_t)pr * IN_F;

    // Hoisted per-row group params: NKG=4 consecutive groups -> one float4 each.
    const int ghi = pr * 64 + (kbase >> 7);
    float4 sh = *(const float4*)(scale + ghi);
    float4 zh = *(const float4*)(zero + ghi);
    float4 sl = *(const float4*)(scale + ghi + HALFG);
    float4 zl = *(const float4*)(zero + ghi + HALFG);
    const float sh_a[4] = {sh.x, sh.y, sh.z, sh.w};
    const float zh_a[4] = {zh.x, zh.y, zh.z, zh.w};
    const float sl_a[4] = {sl.x, sl.y, sl.z, sl.w};
    const float zl_a[4] = {zl.x, zl.y, zl.z, zl.w};
    f16x2 s2h[4], zs2h[4], s2l[4], zs2l[4];
#pragma unroll
    for (int kg = 0; kg < NKG; ++kg) {
        _Float16 s = (_Float16)sh_a[kg];
        _Float16 zs = (_Float16)(-zh_a[kg] * sh_a[kg]);
        s2h[kg][0] = s; s2h[kg][1] = s; zs2h[kg][0] = zs; zs2h[kg][1] = zs;
        s = (_Float16)sl_a[kg];
        zs = (_Float16)(-zl_a[kg] * sl_a[kg]);
        s2l[kg][0] = s; s2l[kg][1] = s; zs2l[kg][0] = zs; zs2l[kg][1] = zs;
    }

#pragma unroll
    for (int kg = 0; kg < NKG; ++kg) {
        // Cluster the group's 8 packed loads: per row a contiguous 512-B burst.
        i32x4 P[8];
        const int* pgk = pk + kbase + kg * 128 + q * 4;
#pragma unroll
        for (int u = 0; u < 8; ++u) P[u] = *(const i32x4*)(pgk + u * 16);

#pragma unroll
        for (int ki = 0; ki < 4; ++ki) {
            const int it = kg * 4 + ki;
            AFrag a0, a1;
            if (FAST) {
                a0.i4 = *(const i32x4*)&alds[it * 64 + lane];
                a1.i4 = *(const i32x4*)&alds[NIT * 64 + it * 64 + lane];
            } else {
                const int k0 = kbase + it * 32 + q * 4;
                float4 x00 = *(const float4*)(xf + (size_t)r * IN_F + k0);
                float4 x01 = *(const float4*)(xf + (size_t)r * IN_F + k0 + 16);
                float4 x10 = *(const float4*)(xf + (size_t)(16 + r) * IN_F + k0);
                float4 x11 = *(const float4*)(xf + (size_t)(16 + r) * IN_F + k0 + 16);
                a0.v[0] = (_Float16)x00.x; a0.v[1] = (_Float16)x00.y;
                a0.v[2] = (_Float16)x00.z; a0.v[3] = (_Float16)x00.w;
                a0.v[4] = (_Float16)x01.x; a0.v[5] = (_Float16)x01.y;
                a0.v[6] = (_Float16)x01.z; a0.v[7] = (_Float16)x01.w;
                a1.v[0] = (_Float16)x10.x; a1.v[1] = (_Float16)x10.y;
                a1.v[2] = (_Float16)x10.z; a1.v[3] = (_Float16)x10.w;
                a1.v[4] = (_Float16)x11.x; a1.v[5] = (_Float16)x11.y;
                a1.v[6] = (_Float16)x11.z; a1.v[7] = (_Float16)x11.w;
            }
            const i32x4 p0 = P[2 * ki];
            const i32x4 p1 = P[2 * ki + 1];
            const unsigned int tt[4] = {
                (unsigned int)p0[0] | ((unsigned int)p0[1] << 16),
                (unsigned int)p0[2] | ((unsigned int)p0[3] << 16),
                (unsigned int)p1[0] | ((unsigned int)p1[1] << 16),
                (unsigned int)p1[2] | ((unsigned int)p1[3] << 16)};
            BFrag bhi, blo;
#pragma unroll
            for (int pi = 0; pi < 4; ++pi) {
                unsigned int hlo = (tt[pi] & 0x000F000Fu) | 0x64006400u;
                unsigned int hhi = ((tt[pi] >> 4) & 0x000F000Fu) | 0x64006400u;
                F16x2U wl, wh;
                wl.v = dq_pair(hlo, s2l[kg], zs2l[kg]);
                wh.v = dq_pair(hhi, s2h[kg], zs2h[kg]);
                blo.u[pi] = wl.u;
                bhi.u[pi] = wh.u;
            }
            acc[0][0] = __builtin_amdgcn_mfma_f32_16x16x32_f16(a0.v, bhi.v, acc[0][0], 0, 0, 0);
            acc[1][0] = __builtin_amdgcn_mfma_f32_16x16x32_f16(a1.v, bhi.v, acc[1][0], 0, 0, 0);
            acc[0][1] = __builtin_amdgcn_mfma_f32_16x16x32_f16(a0.v, blo.v, acc[0][1], 0, 0, 0);
            acc[1][1] = __builtin_amdgcn_mfma_f32_16x16x32_f16(a1.v, blo.v, acc[1][1], 0, 0, 0);
        }
    }

    // Epilogue. C layout: col = lane&15 -> out-row offset; row = q*4+j -> batch.
#pragma unroll
    for (int bt = 0; bt < 2; ++bt) {
#pragma unroll
        for (int hl = 0; hl < 2; ++hl) {
            const int o = nb * 64 + w * 16 + r + hl * (OUT_F / 2);
#pragma unroll
            for (int j = 0; j < 4; ++j) {
                const int b = bt * 16 + q * 4 + j;
                if (FAST) {
                    // fp16 partial, [ks][b][o] layout, nontemporal (single-use)
                    F16U pv; pv.v = (_Float16)acc[bt][hl][j];
                    unsigned short* part = (unsigned short*)outp;
                    __builtin_nontemporal_store(
                        pv.u, part + (size_t)ks * (BATCH * OUT_F) + (size_t)b * OUT_F + o);
                } else {
                    atomicAdd((float*)outp + (size_t)b * OUT_F + o, acc[bt][hl][j]);
                }
            }
        }
    }
}

// Thread per o-PAIR (one dword of 2 fp16): fully-coalesced nontemporal dword
// loads, pk_add accumulate, unpack + bias + float2 store.
template <int KSPLIT>
__global__ __launch_bounds__(256) void reduce_kernel(const unsigned int* __restrict__ part,
                                                     const float* __restrict__ bias,
                                                     float2* __restrict__ out) {
    const int i = blockIdx.x * 256 + threadIdx.x;   // 0..131071 (b,o-pair)
    const int op = i & (OUT_F / 2 - 1);             // o-pair index
    F16x2U s;
    s.u = __builtin_nontemporal_load(part + i);
#pragma unroll
    for (int ks = 1; ks < KSPLIT; ++ks) {
        F16x2U p;
        p.u = __builtin_nontemporal_load(part + (size_t)ks * (BATCH * OUT_F / 2) + i);
        s.v += p.v;                                  // v_pk_add_f16
    }
    const float2 bv = *(const float2*)(bias + op * 2);
    float2 o2;
    o2.x = bv.x + (float)s.v[0];
    o2.y = bv.y + (float)s.v[1];
    out[i] = o2;
}

extern "C" void kernel_launch(void* const* d_in, const int* in_sizes, int n_in,
                              void* d_out, int out_size, void* d_ws, size_t ws_size,
                              hipStream_t stream) {
    (void)in_sizes; (void)n_in; (void)out_size;
    const float* x = (const float*)d_in[0];
    const int* packed = (const int*)d_in[1];
    const float* scale = (const float*)d_in[2];
    const float* zero = (const float*)d_in[3];
    const float* bias = (const float*)d_in[4];
    float* out = (float*)d_out;

    constexpr int KSPLIT = 16;
    const size_t part_bytes = (size_t)KSPLIT * BATCH * OUT_F * sizeof(_Float16);  // 8.4 MB
    const size_t xc_bytes = (size_t)2 * NFRAG_HALF * sizeof(f16x8);
    const size_t need = part_bytes + xc_bytes;

    if (ws_size >= need) {
        _Float16* part = (_Float16*)d_ws;
        f16x8* xc = (f16x8*)((char*)d_ws + part_bytes);
        xcvt_kernel<<<128, 256, 0, stream>>>(x, xc);
        qgemm_kernel<KSPLIT, true><<<dim3(OUT_F / 2 / 64, KSPLIT), 256, 0, stream>>>(
            nullptr, xc, packed, scale, zero, part);
        reduce_kernel<KSPLIT><<<BATCH * OUT_F / 2 / 256, 256, 0, stream>>>(
            (const unsigned int*)part, bias, (float2*)out);
    } else {
        bias_init_kernel<<<256, 256, 0, stream>>>((const float4*)bias, (float4*)out);
        qgemm_kernel<KSPLIT, false><<<dim3(OUT_F / 2 / 64, KSPLIT), 256, 0, stream>>>(
            x, nullptr, packed, scale, zero, out);
    }
}

// Round 17
// 35.671 us; speedup vs baseline: 1.0331x; 1.0331x over previous
//
#include <hip/hip_runtime.h>

#define IN_F 8192
#define OUT_F 8192
#define BATCH 32
#define HALFG ((OUT_F / 2) * (IN_F / 128))  // 262144 groups in the hi-nibble half
#define NFRAG_HALF 16384                    // 256 k-steps * 64 lanes per batch-half

typedef _Float16 f16x2 __attribute__((ext_vector_type(2)));
typedef _Float16 f16x8 __attribute__((ext_vector_type(8)));
typedef float f32x4 __attribute__((ext_vector_type(4)));
typedef int i32x4 __attribute__((ext_vector_type(4)));

union AFrag { f16x8 v; i32x4 i4; };
union BFrag { f16x8 v; unsigned int u[4]; };
union F16x2U { f16x2 v; unsigned int u; };

__device__ inline f16x2 dq_pair(unsigned int h_bits, f16x2 s2, f16x2 zs2) {
    F16x2U h; h.u = h_bits;
    const f16x2 c1024 = {(_Float16)1024.0f, (_Float16)1024.0f};
    f16x2 n = h.v - c1024;          // exact: n in [0,15]
    return n * s2 + zs2;            // v_pk_fma_f16
}

// x fp32 -> fp16, repacked into MFMA A-fragment order.
__global__ __launch_bounds__(256) void xcvt_kernel(const float* __restrict__ x,
                                                   f16x8* __restrict__ xc) {
    int t = blockIdx.x * 256 + threadIdx.x;  // 32768 frags
    int r = t & 15;
    int q = (t >> 4) & 3;
    int k32 = (t >> 6) & 255;
    int half = t >> 14;
    int b = half * 16 + r;
    int kb = k32 * 32 + q * 4;
    float4 x0 = *(const float4*)(x + (size_t)b * IN_F + kb);
    float4 x1 = *(const float4*)(x + (size_t)b * IN_F + kb + 16);
    f16x8 o;
    o[0] = (_Float16)x0.x; o[1] = (_Float16)x0.y; o[2] = (_Float16)x0.z; o[3] = (_Float16)x0.w;
    o[4] = (_Float16)x1.x; o[5] = (_Float16)x1.y; o[6] = (_Float16)x1.z; o[7] = (_Float16)x1.w;
    xc[t] = o;
}

__global__ __launch_bounds__(256) void bias_init_kernel(const float4* __restrict__ bias,
                                                        float4* __restrict__ out) {
    int i = blockIdx.x * 256 + threadIdx.x;
    out[i] = bias[i & 2047];
}

// 4 waves/block; wave owns 16 pair-rows (o, o+4096) x 32 batches. KSPLIT=16.
// LDS-staged xc slice; kg-clustered packed bursts; fp16 partials [ks][b][o]
// with PLAIN stores/loads (R15 config — nt variant regressed, R16).
template <int KSPLIT, bool FAST>
__global__ __launch_bounds__(256, 4) void qgemm_kernel(
    const float* __restrict__ xf, const f16x8* __restrict__ xc,
    const int* __restrict__ packed, const float* __restrict__ scale,
    const float* __restrict__ zero, void* __restrict__ outp) {
    constexpr int KCHUNK = IN_F / KSPLIT;      // 512
    constexpr int NKG = KCHUNK / 128;          // 4 groups
    constexpr int NIT = NKG * 4;               // 16 k-steps of 32
    const int tidx = threadIdx.x;
    const int w = tidx >> 6;
    const int lane = tidx & 63;
    const int r = lane & 15;
    const int q = lane >> 4;
    const int nb = blockIdx.x;                 // 0..63
    const int ks = blockIdx.y;                 // 0..KSPLIT-1
    const int pr = nb * 64 + w * 16 + r;       // packed row < 4096
    const int kbase = ks * KCHUNK;

    __shared__ __align__(16) f16x8 alds[2 * NIT * 64];   // 2048 frags = 32 KB

    if (FAST) {
        const size_t base0 = (size_t)ks * (NIT * 64);    // slice offset per half
#pragma unroll
        for (int j = 0; j < 8; ++j) {
            const int f = j * 256 + tidx;                // 0..2047
            const f16x8* src = (f < NIT * 64)
                                   ? (xc + base0 + f)
                                   : (xc + NFRAG_HALF + base0 + (f - NIT * 64));
            alds[f] = *src;
        }
        __syncthreads();
    }

    f32x4 acc[2][2] = {{{0.f, 0.f, 0.f, 0.f}, {0.f, 0.f, 0.f, 0.f}},
                       {{0.f, 0.f, 0.f, 0.f}, {0.f, 0.f, 0.f, 0.f}}};

    const int* pk = packed + (size_t)pr * IN_F;

    // Hoisted per-row group params: NKG=4 consecutive groups -> one float4 each.
    const int ghi = pr * 64 + (kbase >> 7);
    float4 sh = *(const float4*)(scale + ghi);
    float4 zh = *(const float4*)(zero + ghi);
    float4 sl = *(const float4*)(scale + ghi + HALFG);
    float4 zl = *(const float4*)(zero + ghi + HALFG);
    const float sh_a[4] = {sh.x, sh.y, sh.z, sh.w};
    const float zh_a[4] = {zh.x, zh.y, zh.z, zh.w};
    const float sl_a[4] = {sl.x, sl.y, sl.z, sl.w};
    const float zl_a[4] = {zl.x, zl.y, zl.z, zl.w};
    f16x2 s2h[4], zs2h[4], s2l[4], zs2l[4];
#pragma unroll
    for (int kg = 0; kg < NKG; ++kg) {
        _Float16 s = (_Float16)sh_a[kg];
        _Float16 zs = (_Float16)(-zh_a[kg] * sh_a[kg]);
        s2h[kg][0] = s; s2h[kg][1] = s; zs2h[kg][0] = zs; zs2h[kg][1] = zs;
        s = (_Float16)sl_a[kg];
        zs = (_Float16)(-zl_a[kg] * sl_a[kg]);
        s2l[kg][0] = s; s2l[kg][1] = s; zs2l[kg][0] = zs; zs2l[kg][1] = zs;
    }

#pragma unroll
    for (int kg = 0; kg < NKG; ++kg) {
        // Cluster the group's 8 packed loads: per row a contiguous 512-B burst.
        i32x4 P[8];
        const int* pgk = pk + kbase + kg * 128 + q * 4;
#pragma unroll
        for (int u = 0; u < 8; ++u) P[u] = *(const i32x4*)(pgk + u * 16);

#pragma unroll
        for (int ki = 0; ki < 4; ++ki) {
            const int it = kg * 4 + ki;
            AFrag a0, a1;
            if (FAST) {
                a0.i4 = *(const i32x4*)&alds[it * 64 + lane];
                a1.i4 = *(const i32x4*)&alds[NIT * 64 + it * 64 + lane];
            } else {
                const int k0 = kbase + it * 32 + q * 4;
                float4 x00 = *(const float4*)(xf + (size_t)r * IN_F + k0);
                float4 x01 = *(const float4*)(xf + (size_t)r * IN_F + k0 + 16);
                float4 x10 = *(const float4*)(xf + (size_t)(16 + r) * IN_F + k0);
                float4 x11 = *(const float4*)(xf + (size_t)(16 + r) * IN_F + k0 + 16);
                a0.v[0] = (_Float16)x00.x; a0.v[1] = (_Float16)x00.y;
                a0.v[2] = (_Float16)x00.z; a0.v[3] = (_Float16)x00.w;
                a0.v[4] = (_Float16)x01.x; a0.v[5] = (_Float16)x01.y;
                a0.v[6] = (_Float16)x01.z; a0.v[7] = (_Float16)x01.w;
                a1.v[0] = (_Float16)x10.x; a1.v[1] = (_Float16)x10.y;
                a1.v[2] = (_Float16)x10.z; a1.v[3] = (_Float16)x10.w;
                a1.v[4] = (_Float16)x11.x; a1.v[5] = (_Float16)x11.y;
                a1.v[6] = (_Float16)x11.z; a1.v[7] = (_Float16)x11.w;
            }
            const i32x4 p0 = P[2 * ki];
            const i32x4 p1 = P[2 * ki + 1];
            const unsigned int tt[4] = {
                (unsigned int)p0[0] | ((unsigned int)p0[1] << 16),
                (unsigned int)p0[2] | ((unsigned int)p0[3] << 16),
                (unsigned int)p1[0] | ((unsigned int)p1[1] << 16),
                (unsigned int)p1[2] | ((unsigned int)p1[3] << 16)};
            BFrag bhi, blo;
#pragma unroll
            for (int pi = 0; pi < 4; ++pi) {
                unsigned int hlo = (tt[pi] & 0x000F000Fu) | 0x64006400u;
                unsigned int hhi = ((tt[pi] >> 4) & 0x000F000Fu) | 0x64006400u;
                F16x2U wl, wh;
                wl.v = dq_pair(hlo, s2l[kg], zs2l[kg]);
                wh.v = dq_pair(hhi, s2h[kg], zs2h[kg]);
                blo.u[pi] = wl.u;
                bhi.u[pi] = wh.u;
            }
            acc[0][0] = __builtin_amdgcn_mfma_f32_16x16x32_f16(a0.v, bhi.v, acc[0][0], 0, 0, 0);
            acc[1][0] = __builtin_amdgcn_mfma_f32_16x16x32_f16(a1.v, bhi.v, acc[1][0], 0, 0, 0);
            acc[0][1] = __builtin_amdgcn_mfma_f32_16x16x32_f16(a0.v, blo.v, acc[0][1], 0, 0, 0);
            acc[1][1] = __builtin_amdgcn_mfma_f32_16x16x32_f16(a1.v, blo.v, acc[1][1], 0, 0, 0);
        }
    }

    // Epilogue. C layout: col = lane&15 -> out-row offset; row = q*4+j -> batch.
#pragma unroll
    for (int bt = 0; bt < 2; ++bt) {
#pragma unroll
        for (int hl = 0; hl < 2; ++hl) {
            const int o = nb * 64 + w * 16 + r + hl * (OUT_F / 2);
#pragma unroll
            for (int j = 0; j < 4; ++j) {
                const int b = bt * 16 + q * 4 + j;
                if (FAST) {
                    // fp16 partial, [ks][b][o] layout (plain store, L2/L3-hot)
                    _Float16* part = (_Float16*)outp;
                    part[(size_t)ks * (BATCH * OUT_F) + (size_t)b * OUT_F + o] =
                        (_Float16)acc[bt][hl][j];
                } else {
                    atomicAdd((float*)outp + (size_t)b * OUT_F + o, acc[bt][hl][j]);
                }
            }
        }
    }
}

// Thread per o-PAIR (one dword of 2 fp16): fully-coalesced dword loads,
// pk_add accumulate, unpack + bias + float2 store.
template <int KSPLIT>
__global__ __launch_bounds__(256) void reduce_kernel(const unsigned int* __restrict__ part,
                                                     const float* __restrict__ bias,
                                                     float2* __restrict__ out) {
    const int i = blockIdx.x * 256 + threadIdx.x;   // 0..131071 (b,o-pair)
    const int op = i & (OUT_F / 2 - 1);             // o-pair index
    F16x2U s;
    s.u = part[i];
#pragma unroll
    for (int ks = 1; ks < KSPLIT; ++ks) {
        F16x2U p;
        p.u = part[(size_t)ks * (BATCH * OUT_F / 2) + i];
        s.v += p.v;                                  // v_pk_add_f16
    }
    const float2 bv = *(const float2*)(bias + op * 2);
    float2 o2;
    o2.x = bv.x + (float)s.v[0];
    o2.y = bv.y + (float)s.v[1];
    out[i] = o2;
}

extern "C" void kernel_launch(void* const* d_in, const int* in_sizes, int n_in,
                              void* d_out, int out_size, void* d_ws, size_t ws_size,
                              hipStream_t stream) {
    (void)in_sizes; (void)n_in; (void)out_size;
    const float* x = (const float*)d_in[0];
    const int* packed = (const int*)d_in[1];
    const float* scale = (const float*)d_in[2];
    const float* zero = (const float*)d_in[3];
    const float* bias = (const float*)d_in[4];
    float* out = (float*)d_out;

    constexpr int KSPLIT = 16;
    const size_t part_bytes = (size_t)KSPLIT * BATCH * OUT_F * sizeof(_Float16);  // 8.4 MB
    const size_t xc_bytes = (size_t)2 * NFRAG_HALF * sizeof(f16x8);
    const size_t need = part_bytes + xc_bytes;

    if (ws_size >= need) {
        _Float16* part = (_Float16*)d_ws;
        f16x8* xc = (f16x8*)((char*)d_ws + part_bytes);
        xcvt_kernel<<<128, 256, 0, stream>>>(x, xc);
        qgemm_kernel<KSPLIT, true><<<dim3(OUT_F / 2 / 64, KSPLIT), 256, 0, stream>>>(
            nullptr, xc, packed, scale, zero, part);
        reduce_kernel<KSPLIT><<<BATCH * OUT_F / 2 / 256, 256, 0, stream>>>(
            (const unsigned int*)part, bias, (float2*)out);
    } else {
        bias_init_kernel<<<256, 256, 0, stream>>>((const float4*)bias, (float4*)out);
        qgemm_kernel<KSPLIT, false><<<dim3(OUT_F / 2 / 64, KSPLIT), 256, 0, stream>>>(
            x, nullptr, packed, scale, zero, out);
    }
}